// Round 1
// baseline (1375.832 us; speedup 1.0000x reference)
//
#include <hip/hip_runtime.h>

#define HW (512 * 512)
#define LP 260  // LDS pitch in floats for [8][256] tiles: %4==0 (16B align), breaks bank conflicts

__global__ __launch_bounds__(256) void lwmsa_kernel(
    const float* __restrict__ x,
    const float* __restrict__ w,
    float* __restrict__ out)
{
    const int win  = blockIdx.x;       // 0..4095
    const int b    = win >> 10;
    const int wrow = (win >> 5) & 31;
    const int wcol = win & 31;
    const int n    = threadIdx.x;      // 0..255 = position in window (r*16 + c)

    const int base = b * (64 * HW) + (wrow * 16 + (n >> 4)) * 512 + wcol * 16 + (n & 15);

    // ---- load this thread's x column (64 channels) into registers ----
    float xr[64];
    #pragma unroll
    for (int c = 0; c < 64; ++c)
        xr[c] = x[base + c * HW];

    __shared__ float kf_s[8 * LP];
    __shared__ float v_s [8 * LP];
    __shared__ float kvp [4 * 64];
    __shared__ float kv_s[64];
    __shared__ float tp  [4];

    float feat[8];
    #pragma unroll
    for (int d = 0; d < 8; ++d) feat[d] = 0.f;

    for (int i = 0; i < 8; ++i) {
        // ---- qkv projection for head i: 24 dots of length 64, w via uniform (scalar) loads ----
        float aq[8], ak[8], av[8];
        #pragma unroll
        for (int d = 0; d < 8; ++d) { aq[d] = 0.f; ak[d] = 0.f; av[d] = 0.f; }

        const float4* wq4 = (const float4*)(w + (0 * 64 + i * 8) * 64);
        const float4* wk4 = (const float4*)(w + (1 * 64 + i * 8) * 64);
        const float4* wv4 = (const float4*)(w + (2 * 64 + i * 8) * 64);

        #pragma unroll
        for (int c4 = 0; c4 < 16; ++c4) {
            const float x0 = xr[4 * c4 + 0];
            const float x1 = xr[4 * c4 + 1];
            const float x2 = xr[4 * c4 + 2];
            const float x3 = xr[4 * c4 + 3];
            #pragma unroll
            for (int d = 0; d < 8; ++d) {
                float4 t;
                t = wq4[d * 16 + c4];
                aq[d] = fmaf(t.x, x0, aq[d]); aq[d] = fmaf(t.y, x1, aq[d]);
                aq[d] = fmaf(t.z, x2, aq[d]); aq[d] = fmaf(t.w, x3, aq[d]);
                t = wk4[d * 16 + c4];
                ak[d] = fmaf(t.x, x0, ak[d]); ak[d] = fmaf(t.y, x1, ak[d]);
                ak[d] = fmaf(t.z, x2, ak[d]); ak[d] = fmaf(t.w, x3, ak[d]);
                t = wv4[d * 16 + c4];
                av[d] = fmaf(t.x, x0, av[d]); av[d] = fmaf(t.y, x1, av[d]);
                av[d] = fmaf(t.z, x2, av[d]); av[d] = fmaf(t.w, x3, av[d]);
            }
        }

        if (i > 0) {
            #pragma unroll
            for (int d = 0; d < 8; ++d) {
                aq[d] += feat[d]; ak[d] += feat[d]; av[d] += feat[d];
            }
        }

        // ---- elu1 + per-thread row sums ----
        float qf[8], kf[8];
        float Sq = 0.f, tpart = 0.f;
        #pragma unroll
        for (int d = 0; d < 8; ++d) {
            qf[d] = aq[d] > 0.f ? aq[d] + 1.f : __expf(aq[d]);
            kf[d] = ak[d] > 0.f ? ak[d] + 1.f : __expf(ak[d]);
            Sq    += qf[d];
            tpart += kf[d];
        }

        __syncthreads();  // B1: everyone done reading prev head's kf_s/v_s/kv_s/tp

        #pragma unroll
        for (int d = 0; d < 8; ++d) {
            kf_s[d * LP + n] = kf[d];
            v_s [d * LP + n] = av[d];
        }

        #pragma unroll
        for (int off = 1; off < 64; off <<= 1)
            tpart += __shfl_xor(tpart, off, 64);
        if ((n & 63) == 0) tp[n >> 6] = tpart;

        __syncthreads();  // B2: kf_s/v_s/tp visible

        // ---- kv[d][c] = sum_n kf[d][n]*v[c][n]; remap threads to (group, d, c) ----
        {
            const int dc  = n & 63;
            const int grp = n >> 6;
            const float4* kr = (const float4*)(kf_s + (dc >> 3) * LP + grp * 64);
            const float4* vr = (const float4*)(v_s  + (dc & 7)  * LP + grp * 64);
            float s0 = 0.f, s1 = 0.f, s2 = 0.f, s3 = 0.f;
            #pragma unroll
            for (int j = 0; j < 16; ++j) {
                const float4 kk = kr[j];
                const float4 vv = vr[j];
                s0 = fmaf(kk.x, vv.x, s0);
                s1 = fmaf(kk.y, vv.y, s1);
                s2 = fmaf(kk.z, vv.z, s2);
                s3 = fmaf(kk.w, vv.w, s3);
            }
            kvp[grp * 64 + dc] = (s0 + s1) + (s2 + s3);
        }

        __syncthreads();  // B3: kvp visible

        if (n < 64)
            kv_s[n] = (kvp[0 * 64 + n] + kvp[1 * 64 + n]) +
                      (kvp[2 * 64 + n] + kvp[3 * 64 + n]);

        __syncthreads();  // B4: kv_s visible

        const float T  = ((tp[0] + tp[1]) + (tp[2] + tp[3])) + 8.0f * 1e-6f;
        const float zi = 1.0f / (Sq * T);

        #pragma unroll
        for (int d = 0; d < 8; ++d) feat[d] = 0.f;
        #pragma unroll
        for (int d = 0; d < 8; ++d) {
            const float qd = qf[d];
            const float4 a  = ((const float4*)(kv_s + d * 8))[0];
            const float4 bb = ((const float4*)(kv_s + d * 8))[1];
            feat[0] = fmaf(qd, a.x,  feat[0]);
            feat[1] = fmaf(qd, a.y,  feat[1]);
            feat[2] = fmaf(qd, a.z,  feat[2]);
            feat[3] = fmaf(qd, a.w,  feat[3]);
            feat[4] = fmaf(qd, bb.x, feat[4]);
            feat[5] = fmaf(qd, bb.y, feat[5]);
            feat[6] = fmaf(qd, bb.z, feat[6]);
            feat[7] = fmaf(qd, bb.w, feat[7]);
        }
        #pragma unroll
        for (int d = 0; d < 8; ++d) {
            feat[d] *= zi;
            out[base + (i * 8 + d) * HW] = feat[d];
        }
    }
}

extern "C" void kernel_launch(void* const* d_in, const int* in_sizes, int n_in,
                              void* d_out, int out_size, void* d_ws, size_t ws_size,
                              hipStream_t stream) {
    const float* x  = (const float*)d_in[0];
    const float* w  = (const float*)d_in[1];
    float* out      = (float*)d_out;
    lwmsa_kernel<<<dim3(4096), dim3(256), 0, stream>>>(x, w, out);
}

// Round 2
// 464.807 us; speedup vs baseline: 2.9600x; 2.9600x over previous
//
#include <hip/hip_runtime.h>

#define HW (512 * 512)
#define XP 72    // xh/xl pitch (bf16 elems): 144 B row stride -> conflict-free b128 frag reads
#define QP 260   // qk pitch (floats): 16B aligned, odd-dword-ish banking, float4-clean

typedef __bf16 bf16;
typedef __attribute__((ext_vector_type(8))) __bf16 bf16x8;
typedef __attribute__((ext_vector_type(4))) __bf16 bf16x4;
typedef __attribute__((ext_vector_type(4))) float f32x4;

__device__ __forceinline__ void cvt_split(float f, bf16& h, bf16& l) {
    h = (bf16)f;
    l = (bf16)(f - (float)h);
}

__global__ __launch_bounds__(256) void lwmsa_kernel(
    const float* __restrict__ x,
    const float* __restrict__ w,
    float* __restrict__ out)
{
    const int win  = blockIdx.x;       // 0..4095
    const int b    = win >> 10;
    const int wrow = (win >> 5) & 31;
    const int wcol = win & 31;
    const int n    = threadIdx.x;      // 0..255 = pixel in window
    const int lane = n & 63;
    const int wvid = n >> 6;           // wave 0..3
    const int r16  = n & 15;           // fragment row/col index
    const int g16  = (n >> 4) & 3;     // fragment k-group

    const int base = b * (64 * HW) + (wrow * 16 + (n >> 4)) * 512 + wcol * 16 + (n & 15);

    __shared__ bf16  xh[256 * XP];     // X hi, [px][ch]
    __shared__ bf16  xl[256 * XP];     // X lo
    __shared__ float qk[48 * QP];      // 2 heads x (q8,k8,v8) rows, [row][px]
    __shared__ float kvp[4 * 64];
    __shared__ float kv_s[64];
    __shared__ float tp[4];

    // ---- stage X into LDS as bf16 hi/lo (once) ----
    #pragma unroll
    for (int c4 = 0; c4 < 16; ++c4) {
        bf16x4 h4, l4;
        #pragma unroll
        for (int j = 0; j < 4; ++j) {
            const float f = x[base + (4 * c4 + j) * HW];
            bf16 h, l;
            cvt_split(f, h, l);
            h4[j] = h; l4[j] = l;
        }
        *(bf16x4*)&xh[n * XP + 4 * c4] = h4;
        *(bf16x4*)&xl[n * XP + 4 * c4] = l4;
    }

    float feat[8];
    #pragma unroll
    for (int d = 0; d < 8; ++d) feat[d] = 0.f;

    __syncthreads();  // X staged

    for (int g = 0; g < 4; ++g) {      // head pair (2g, 2g+1)
        // ---- MFMA: project 48 rows (qkv of both heads) x 256 px, K=64, 3-term split ----
        f32x4 acc[3][4];
        #pragma unroll
        for (int mt = 0; mt < 3; ++mt)
            #pragma unroll
            for (int nt = 0; nt < 4; ++nt)
                acc[mt][nt] = (f32x4){0.f, 0.f, 0.f, 0.f};

        #pragma unroll
        for (int ks = 0; ks < 2; ++ks) {
            bf16x8 ah[3], al[3];
            #pragma unroll
            for (int mt = 0; mt < 3; ++mt) {
                const int mloc = mt * 16 + r16;                 // 0..47 within group
                const int head = 2 * g + (mloc >= 24 ? 1 : 0);
                const int mm   = (mloc >= 24) ? mloc - 24 : mloc;
                const int grow = (mm >> 3) * 64 + head * 8 + (mm & 7);  // row in w[192][64]
                const float4* wp = (const float4*)(w + grow * 64 + ks * 32 + g16 * 8);
                const float4 wa = wp[0];
                const float4 wb = wp[1];
                bf16 h, l;
                cvt_split(wa.x, h, l); ah[mt][0] = h; al[mt][0] = l;
                cvt_split(wa.y, h, l); ah[mt][1] = h; al[mt][1] = l;
                cvt_split(wa.z, h, l); ah[mt][2] = h; al[mt][2] = l;
                cvt_split(wa.w, h, l); ah[mt][3] = h; al[mt][3] = l;
                cvt_split(wb.x, h, l); ah[mt][4] = h; al[mt][4] = l;
                cvt_split(wb.y, h, l); ah[mt][5] = h; al[mt][5] = l;
                cvt_split(wb.z, h, l); ah[mt][6] = h; al[mt][6] = l;
                cvt_split(wb.w, h, l); ah[mt][7] = h; al[mt][7] = l;
            }
            #pragma unroll
            for (int nt = 0; nt < 4; ++nt) {
                const int px = (wvid * 4 + nt) * 16 + r16;
                const int ko = ks * 32 + g16 * 8;
                const bf16x8 bh = *(const bf16x8*)&xh[px * XP + ko];
                const bf16x8 bl = *(const bf16x8*)&xl[px * XP + ko];
                #pragma unroll
                for (int mt = 0; mt < 3; ++mt) {
                    acc[mt][nt] = __builtin_amdgcn_mfma_f32_16x16x32_bf16(ah[mt], bh, acc[mt][nt], 0, 0, 0);
                    acc[mt][nt] = __builtin_amdgcn_mfma_f32_16x16x32_bf16(ah[mt], bl, acc[mt][nt], 0, 0, 0);
                    acc[mt][nt] = __builtin_amdgcn_mfma_f32_16x16x32_bf16(al[mt], bh, acc[mt][nt], 0, 0, 0);
                }
            }
        }

        // ---- stage projections to LDS: D col=lane&15 -> px, row=(lane>>4)*4+r ----
        #pragma unroll
        for (int mt = 0; mt < 3; ++mt)
            #pragma unroll
            for (int nt = 0; nt < 4; ++nt) {
                const int px = (wvid * 4 + nt) * 16 + r16;
                const int r0 = mt * 16 + g16 * 4;
                #pragma unroll
                for (int r = 0; r < 4; ++r)
                    qk[(r0 + r) * QP + px] = acc[mt][nt][r];
            }
        __syncthreads();  // projections staged

        // ---- serial per-head math (same as verified R1 kernel) ----
        #pragma unroll
        for (int lh = 0; lh < 2; ++lh) {
            const int lb = lh * 24;

            float aq[8], ak[8], av[8];
            #pragma unroll
            for (int d = 0; d < 8; ++d) {
                aq[d] = qk[(lb + d)      * QP + n] + feat[d];
                ak[d] = qk[(lb + 8 + d)  * QP + n] + feat[d];
                av[d] = qk[(lb + 16 + d) * QP + n] + feat[d];
            }

            float qf[8], kf[8];
            float Sq = 0.f, tpart = 0.f;
            #pragma unroll
            for (int d = 0; d < 8; ++d) {
                qf[d] = aq[d] > 0.f ? aq[d] + 1.f : __expf(aq[d]);
                kf[d] = ak[d] > 0.f ? ak[d] + 1.f : __expf(ak[d]);
                Sq    += qf[d];
                tpart += kf[d];
            }

            __syncthreads();  // B1: prev head's tp/kv_s/kvp reads done

            #pragma unroll
            for (int d = 0; d < 8; ++d) {
                qk[(lb + 8 + d)  * QP + n] = kf[d];   // overwrite k rows with elu'd k
                qk[(lb + 16 + d) * QP + n] = av[d];   // overwrite v rows with v+feat
            }

            #pragma unroll
            for (int off = 1; off < 64; off <<= 1)
                tpart += __shfl_xor(tpart, off, 64);
            if (lane == 0) tp[wvid] = tpart;

            __syncthreads();  // B2: kf/v/tp staged

            {
                const int dc  = n & 63;
                const int grp = n >> 6;
                const float4* kr = (const float4*)(qk + (lb + 8 + (dc >> 3))  * QP + grp * 64);
                const float4* vr = (const float4*)(qk + (lb + 16 + (dc & 7)) * QP + grp * 64);
                float s0 = 0.f, s1 = 0.f, s2 = 0.f, s3 = 0.f;
                #pragma unroll
                for (int j = 0; j < 16; ++j) {
                    const float4 kk = kr[j];
                    const float4 vv = vr[j];
                    s0 = fmaf(kk.x, vv.x, s0);
                    s1 = fmaf(kk.y, vv.y, s1);
                    s2 = fmaf(kk.z, vv.z, s2);
                    s3 = fmaf(kk.w, vv.w, s3);
                }
                kvp[grp * 64 + dc] = (s0 + s1) + (s2 + s3);
            }

            __syncthreads();  // B3

            if (n < 64)
                kv_s[n] = (kvp[n] + kvp[64 + n]) + (kvp[128 + n] + kvp[192 + n]);

            __syncthreads();  // B4

            const float T  = ((tp[0] + tp[1]) + (tp[2] + tp[3])) + 8.0f * 1e-6f;
            const float zi = 1.0f / (Sq * T);

            #pragma unroll
            for (int d = 0; d < 8; ++d) feat[d] = 0.f;
            #pragma unroll
            for (int d = 0; d < 8; ++d) {
                const float qd = qf[d];
                const float4 a  = ((const float4*)(kv_s + d * 8))[0];
                const float4 bb = ((const float4*)(kv_s + d * 8))[1];
                feat[0] = fmaf(qd, a.x,  feat[0]);
                feat[1] = fmaf(qd, a.y,  feat[1]);
                feat[2] = fmaf(qd, a.z,  feat[2]);
                feat[3] = fmaf(qd, a.w,  feat[3]);
                feat[4] = fmaf(qd, bb.x, feat[4]);
                feat[5] = fmaf(qd, bb.y, feat[5]);
                feat[6] = fmaf(qd, bb.z, feat[6]);
                feat[7] = fmaf(qd, bb.w, feat[7]);
            }

            const int ch0 = (2 * g + lh) * 8;
            #pragma unroll
            for (int d = 0; d < 8; ++d) {
                feat[d] *= zi;
                out[base + (ch0 + d) * HW] = feat[d];
            }
        }
    }
}

extern "C" void kernel_launch(void* const* d_in, const int* in_sizes, int n_in,
                              void* d_out, int out_size, void* d_ws, size_t ws_size,
                              hipStream_t stream) {
    const float* x  = (const float*)d_in[0];
    const float* w  = (const float*)d_in[1];
    float* out      = (float*)d_out;
    lwmsa_kernel<<<dim3(4096), dim3(256), 0, stream>>>(x, w, out);
}

// Round 3
// 303.478 us; speedup vs baseline: 4.5335x; 1.5316x over previous
//
#include <hip/hip_runtime.h>

#define HW (512 * 512)
#define QP 260   // qk pitch (floats): float4-clean, 260%32=4 -> staggered banks

typedef __bf16 bf16;
typedef __attribute__((ext_vector_type(8))) __bf16 bf16x8;
typedef __attribute__((ext_vector_type(4))) float f32x4;

__device__ __forceinline__ void cvt_split(float f, bf16& h, bf16& l) {
    h = (bf16)f;
    l = (bf16)(f - (float)h);
}

__global__ __launch_bounds__(256, 2) void lwmsa_kernel(
    const float* __restrict__ x,
    const float* __restrict__ w,
    float* __restrict__ out)
{
    const int win  = blockIdx.x;       // 0..4095
    const int b    = win >> 10;
    const int wrow = (win >> 5) & 31;
    const int wcol = win & 31;
    const int n    = threadIdx.x;      // 0..255 = pixel in window
    const int lane = n & 63;
    const int wvid = n >> 6;           // wave 0..3
    const int c16  = lane & 15;        // fragment row/col index
    const int q4   = lane >> 4;        // fragment k-quarter

    const int base = b * (64 * HW) + (wrow * 16 + (n >> 4)) * 512 + wcol * 16 + (n & 15);
    const int xwin = b * (64 * HW) + (wrow * 16) * 512 + wcol * 16;   // window origin

    __shared__ float qk[48 * QP];      // 2 heads x (q8,k8,v8) rows, [row][px]
    __shared__ float kvp[4 * 64];
    __shared__ float kv_s[64];
    __shared__ float tp[4];

    // ---- A-fragments (X), hi/lo, straight from global into registers ----
    // M-tile (wvid,mt) = window row wvid*4+mt; lane holds px-col c16, k = ks*32+q4*8+j
    bf16x8 ah[2][4], al[2][4];
    #pragma unroll
    for (int ks = 0; ks < 2; ++ks)
        #pragma unroll
        for (int mt = 0; mt < 4; ++mt) {
            const int row = wvid * 4 + mt;
            const float* xp = x + xwin + row * 512 + c16 + (ks * 32 + q4 * 8) * HW;
            #pragma unroll
            for (int j = 0; j < 8; ++j) {
                bf16 h, l;
                cvt_split(xp[j * HW], h, l);
                ah[ks][mt][j] = h;
                al[ks][mt][j] = l;
            }
        }

    float feat[8];
    #pragma unroll
    for (int d = 0; d < 8; ++d) feat[d] = 0.f;

    for (int g = 0; g < 4; ++g) {      // head pair (2g, 2g+1)
        // ---- MFMA: D[px][qkvrow] = X . W^T, 48 rows, K=64, 3-term split ----
        f32x4 acc[4][3];
        #pragma unroll
        for (int mt = 0; mt < 4; ++mt)
            #pragma unroll
            for (int nt = 0; nt < 3; ++nt)
                acc[mt][nt] = (f32x4){0.f, 0.f, 0.f, 0.f};

        #pragma unroll
        for (int ks = 0; ks < 2; ++ks) {
            #pragma unroll
            for (int nt = 0; nt < 3; ++nt) {
                const int ml   = nt * 16 + c16;                 // 0..47 pair-local row
                const int head = 2 * g + (ml >= 24 ? 1 : 0);
                const int mm   = (ml >= 24) ? ml - 24 : ml;
                const int grow = (mm >> 3) * 64 + head * 8 + (mm & 7);  // row in w[192][64]
                const float4* wp = (const float4*)(w + grow * 64 + ks * 32 + q4 * 8);
                const float4 wa = wp[0];
                const float4 wb = wp[1];
                bf16x8 bh, bl;
                bf16 h, l;
                cvt_split(wa.x, h, l); bh[0] = h; bl[0] = l;
                cvt_split(wa.y, h, l); bh[1] = h; bl[1] = l;
                cvt_split(wa.z, h, l); bh[2] = h; bl[2] = l;
                cvt_split(wa.w, h, l); bh[3] = h; bl[3] = l;
                cvt_split(wb.x, h, l); bh[4] = h; bl[4] = l;
                cvt_split(wb.y, h, l); bh[5] = h; bl[5] = l;
                cvt_split(wb.z, h, l); bh[6] = h; bl[6] = l;
                cvt_split(wb.w, h, l); bh[7] = h; bl[7] = l;
                #pragma unroll
                for (int mt = 0; mt < 4; ++mt) {
                    acc[mt][nt] = __builtin_amdgcn_mfma_f32_16x16x32_bf16(ah[ks][mt], bh, acc[mt][nt], 0, 0, 0);
                    acc[mt][nt] = __builtin_amdgcn_mfma_f32_16x16x32_bf16(al[ks][mt], bh, acc[mt][nt], 0, 0, 0);
                    acc[mt][nt] = __builtin_amdgcn_mfma_f32_16x16x32_bf16(ah[ks][mt], bl, acc[mt][nt], 0, 0, 0);
                }
            }
        }

        // ---- stage D to LDS: lane holds row=nt*16+c16, px=(wvid*4+mt)*16+q4*4+reg ----
        #pragma unroll
        for (int mt = 0; mt < 4; ++mt)
            #pragma unroll
            for (int nt = 0; nt < 3; ++nt) {
                const int row = nt * 16 + c16;
                const int px  = (wvid * 4 + mt) * 16 + q4 * 4;
                *(float4*)&qk[row * QP + px] = *(float4*)&acc[mt][nt];
            }
        __syncthreads();  // projections staged

        // ---- serial per-head math (verified structure) ----
        #pragma unroll
        for (int lh = 0; lh < 2; ++lh) {
            const int lb = lh * 24;

            float aq[8], ak[8], av[8];
            #pragma unroll
            for (int d = 0; d < 8; ++d) {
                aq[d] = qk[(lb + d)      * QP + n] + feat[d];
                ak[d] = qk[(lb + 8 + d)  * QP + n] + feat[d];
                av[d] = qk[(lb + 16 + d) * QP + n] + feat[d];
            }

            float qf[8], kf[8];
            float Sq = 0.f, tpart = 0.f;
            #pragma unroll
            for (int d = 0; d < 8; ++d) {
                qf[d] = aq[d] > 0.f ? aq[d] + 1.f : __expf(aq[d]);
                kf[d] = ak[d] > 0.f ? ak[d] + 1.f : __expf(ak[d]);
                Sq    += qf[d];
                tpart += kf[d];
            }

            __syncthreads();  // B1: prev head's tp/kv_s/kvp reads done

            #pragma unroll
            for (int d = 0; d < 8; ++d) {
                qk[(lb + 8 + d)  * QP + n] = kf[d];   // k rows -> elu'd k
                qk[(lb + 16 + d) * QP + n] = av[d];   // v rows -> v+feat
            }

            #pragma unroll
            for (int off = 1; off < 64; off <<= 1)
                tpart += __shfl_xor(tpart, off, 64);
            if (lane == 0) tp[wvid] = tpart;

            __syncthreads();  // B2: kf/v/tp staged

            {
                const int dc  = lane;
                const int grp = wvid;
                const float4* kr = (const float4*)(qk + (lb + 8 + (dc >> 3))  * QP + grp * 64);
                const float4* vr = (const float4*)(qk + (lb + 16 + (dc & 7)) * QP + grp * 64);
                float s0 = 0.f, s1 = 0.f, s2 = 0.f, s3 = 0.f;
                #pragma unroll
                for (int j = 0; j < 16; ++j) {
                    const float4 kk = kr[j];
                    const float4 vv = vr[j];
                    s0 = fmaf(kk.x, vv.x, s0);
                    s1 = fmaf(kk.y, vv.y, s1);
                    s2 = fmaf(kk.z, vv.z, s2);
                    s3 = fmaf(kk.w, vv.w, s3);
                }
                kvp[grp * 64 + dc] = (s0 + s1) + (s2 + s3);
            }

            __syncthreads();  // B3

            if (n < 64)
                kv_s[n] = (kvp[n] + kvp[64 + n]) + (kvp[128 + n] + kvp[192 + n]);

            __syncthreads();  // B4

            const float T  = ((tp[0] + tp[1]) + (tp[2] + tp[3])) + 8.0f * 1e-6f;
            const float zi = 1.0f / (Sq * T);

            #pragma unroll
            for (int d = 0; d < 8; ++d) feat[d] = 0.f;
            #pragma unroll
            for (int d = 0; d < 8; ++d) {
                const float qd = qf[d];
                const float4 a  = ((const float4*)(kv_s + d * 8))[0];
                const float4 bb = ((const float4*)(kv_s + d * 8))[1];
                feat[0] = fmaf(qd, a.x,  feat[0]);
                feat[1] = fmaf(qd, a.y,  feat[1]);
                feat[2] = fmaf(qd, a.z,  feat[2]);
                feat[3] = fmaf(qd, a.w,  feat[3]);
                feat[4] = fmaf(qd, bb.x, feat[4]);
                feat[5] = fmaf(qd, bb.y, feat[5]);
                feat[6] = fmaf(qd, bb.z, feat[6]);
                feat[7] = fmaf(qd, bb.w, feat[7]);
            }

            const int ch0 = (2 * g + lh) * 8;
            #pragma unroll
            for (int d = 0; d < 8; ++d) {
                feat[d] *= zi;
                out[base + (ch0 + d) * HW] = feat[d];
            }
        }
    }
}

extern "C" void kernel_launch(void* const* d_in, const int* in_sizes, int n_in,
                              void* d_out, int out_size, void* d_ws, size_t ws_size,
                              hipStream_t stream) {
    const float* x  = (const float*)d_in[0];
    const float* w  = (const float*)d_in[1];
    float* out      = (float*)d_out;
    lwmsa_kernel<<<dim3(4096), dim3(256), 0, stream>>>(x, w, out);
}